// Round 14
// baseline (881.365 us; speedup 1.0000x reference)
//
#include <hip/hip_runtime.h>
#include <stdint.h>

typedef unsigned short u16;
typedef unsigned int u32;
typedef __attribute__((ext_vector_type(8))) short bf16x8;
typedef __attribute__((ext_vector_type(4))) float f32x4;
typedef __attribute__((ext_vector_type(4))) u32 u32x4;

#define DEV static __device__ __forceinline__

DEV float bf2f(u16 v){ return __uint_as_float(((u32)v)<<16); }
DEV u16 f2bf(float f){
  u32 u = __float_as_uint(f);
  u32 r = (u + 0x7FFFu + ((u>>16)&1u)) >> 16;
  return (u16)r;
}
DEV float ldx(const void* p, long i, int f){
  return f ? ((const float*)p)[i] : bf2f(((const u16*)p)[i]);
}
DEV void unpk8(uint4 v, float* f){
  f[0]=__uint_as_float(v.x<<16); f[1]=__uint_as_float(v.x&0xFFFF0000u);
  f[2]=__uint_as_float(v.y<<16); f[3]=__uint_as_float(v.y&0xFFFF0000u);
  f[4]=__uint_as_float(v.z<<16); f[5]=__uint_as_float(v.z&0xFFFF0000u);
  f[6]=__uint_as_float(v.w<<16); f[7]=__uint_as_float(v.w&0xFFFF0000u);
}
DEV int iabs(int a){ return a<0? -a : a; }

// ======================= dtype probe / guards =======================
__global__ void detect_k(const void* x, int* dflag){
  const u16* p = (const u16*)x;
  int t = threadIdx.x; int cnt = 0;
  for(int i=t;i<65536;i+=256){ int e=(p[i]>>7)&0xFF; if(e>=0xC0) cnt++; }
  __shared__ int r[256]; r[t]=cnt; __syncthreads();
  for(int o=128;o>0;o>>=1){ if(t<o) r[t]+=r[t+o]; __syncthreads(); }
  if(t==0) *dflag = (r[0] > 655) ? 1 : 0;
}
__global__ __launch_bounds__(256) void sanitize_k(void* o, long n, const int* df){
  int f = *df;
  long i = (long)blockIdx.x*256 + threadIdx.x;
  long st = (long)gridDim.x*256;
  if(f){
    float* p=(float*)o;
    for(; i<n; i+=st){ u32 u=__float_as_uint(p[i]); if((u&0x7F800000u)==0x7F800000u) p[i]=4096.f; }
  } else {
    u16* p=(u16*)o;
    u16 c = f2bf(4096.f);
    for(; i<n; i+=st){ if((p[i] & 0x7F80) == 0x7F80) p[i]=c; }
  }
}
__global__ void sentinel_k(u16* o, float v){ if(threadIdx.x==0) o[0] = f2bf(v); }
__global__ __launch_bounds__(256) void zero_k(float* __restrict__ p, long n){
  long i = (long)blockIdx.x*256 + threadIdx.x;
  long st = (long)gridDim.x*256;
  for(; i<n; i+=st) p[i]=0.f;
}

// ======================= data movement =======================
__global__ __launch_bounds__(256) void transp_k(const void* x, u16* __restrict__ xT, const int* df){
  __shared__ float T[32][33];
  int f = *df;
  int p0 = blockIdx.x*32, c0 = blockIdx.y*32, b = blockIdx.z;
  int tx = threadIdx.x & 31, ty = threadIdx.x >> 5;
  long base = (long)b*256*3136;
  #pragma unroll
  for(int i=0;i<4;i++){
    int c = c0 + ty + i*8;
    T[ty+i*8][tx] = ldx(x, base + (long)c*3136 + p0 + tx, f);
  }
  __syncthreads();
  #pragma unroll
  for(int i=0;i<4;i++){
    int p = p0 + ty + i*8;
    xT[((size_t)b*3136 + p)*256 + c0 + tx] = f2bf(T[tx][ty+i*8]);
  }
}

// batched over blockIdx.y = b
__global__ __launch_bounds__(256) void im2col_bt_k(const void* in, long bstride, u16* __restrict__ out,
                                                   int Cin, int isInput, const int* df){
  int f = isInput ? *df : 0;
  int K9 = Cin*9;
  int total = 784*K9;
  int id = blockIdx.x*256 + threadIdx.x;
  if(id>=total) return;
  long off = (long)blockIdx.y * bstride;
  u16* op = out + (size_t)blockIdx.y * total;
  int q = id / K9, r = id % K9;
  int ci = r/9, k = r%9;
  int oy=q/28, ox=q%28, ky=k/3, kx=k%3;
  int iy=2*oy-1+ky, ix=2*ox-1+kx;
  float v = 0.f;
  if((u32)iy<56u && (u32)ix<56u) v = ldx(in, off + (long)ci*3136 + iy*56+ix, f);
  op[id] = f2bf(v);
}

__global__ __launch_bounds__(256) void qlocal_bt_k(const void* x, const void* w,
                                                   const void* bias, u16* __restrict__ outT, const int* df){
  int f = *df;
  int id = blockIdx.x*256 + threadIdx.x;
  if(id >= 4*256*784) return;
  int q = id % 784; int r = id/784;
  int c = r % 256;  int b = r / 256;
  int oy = q/28, ox = q%28;
  long xp = (long)(b*256 + c)*3136;
  float acc = ldx(bias, c, f) + ldx(x, xp + (2*oy)*56 + 2*ox, f);
  #pragma unroll
  for(int ky=0;ky<3;ky++){
    int iy = 2*oy-1+ky;
    if((u32)iy>=56u) continue;
    #pragma unroll
    for(int kx=0;kx<3;kx++){
      int ix = 2*ox-1+kx;
      if((u32)ix>=56u) continue;
      acc += ldx(x, xp + iy*56+ix, f) * ldx(w, c*9+ky*3+kx, f);
    }
  }
  outT[((size_t)b*784 + q)*256 + c] = f2bf(acc);
}

// hardswish(obuf_fp32 + vloc) -> hbufT[b][q][c]
__global__ __launch_bounds__(256) void hs_addT_k(const float* __restrict__ a, const u16* __restrict__ bsrc,
                                                 u16* __restrict__ outT){
  __shared__ float T[32][33];
  int q0 = blockIdx.x*32, c0 = blockIdx.y*32, b = blockIdx.z;
  int tx = threadIdx.x&31, ty = threadIdx.x>>5;
  #pragma unroll
  for(int i=0;i<4;i++){
    int c = c0+ty+i*8;
    int q = q0+tx;
    float s = 0.f;
    if(q < 784){
      size_t e = ((size_t)b*512 + c)*784 + q;
      s = a[e] + bf2f(bsrc[e]);
      float cl = fminf(fmaxf(s+3.f,0.f),6.f);
      s = s*cl*(1.f/6.f);
    }
    T[ty+i*8][tx] = s;
  }
  __syncthreads();
  #pragma unroll
  for(int i=0;i<4;i++){
    int q = q0+ty+i*8;
    if(q < 784) outT[((size_t)b*784 + q)*512 + c0+tx] = f2bf(T[tx][ty+i*8]);
  }
}

// ======================= MFMA GEMM (BT convention) =======================
// z decomposed as zd*zdiv + zm: offsets = zm*s + zd*s2 (A/bias use zm only).
// splitK>1: blockIdx.y = my*splitK + kc; fp32 atomicAdd C writes (outF32
// required); bias added only by kc==0 blocks.
// ntB: non-temporal B loads. outF32: float C (sC/sC2 count floats).
__global__ __launch_bounds__(256) void gemm_mfma_k(const void* A, const u16* __restrict__ BT,
                                                   void* C, const void* bias,
                                                   int M, int N, int K, int ldB,
                                                   long sA, long sB, long sC, int sBias,
                                                   long sB2, long sC2, int zdiv,
                                                   int splitK, int ntB, int outF32, const int* df){
  __shared__ u16 As[64][40];
  __shared__ u16 Bs[64][40];
  int f = *df;
  int z = blockIdx.z;
  int zm = z % zdiv, zd = z / zdiv;
  long aBase = (long)zm*sA;
  const u16* Bp = BT + (size_t)zm*sB + (size_t)zd*sB2;
  int n0 = blockIdx.x*64;
  int m0, kStart, kEnd;
  bool addB;
  if(splitK > 1){
    int my = blockIdx.y / splitK;
    int kc = blockIdx.y % splitK;
    m0 = my*64;
    int kLen = K/splitK;
    kStart = kc*kLen;
    kEnd = kStart + kLen;
    addB = (bias != nullptr) && (kc == 0);
  } else {
    m0 = blockIdx.y*64;
    kStart = 0; kEnd = K;
    addB = (bias != nullptr);
  }
  int t = threadIdx.x;
  int sm = t>>2, sk = (t&3)*8;
  int w = t>>6, l = t&63;
  int lm = l&15, lq = l>>4;
  f32x4 acc0={0.f,0.f,0.f,0.f}, acc1=acc0, acc2=acc0, acc3=acc0;
  bool bok = (n0 + sm) < N;
  for(int kk=kStart; kk<kEnd; kk+=32){
    {
      long off = aBase + (long)(m0+sm)*K + kk + sk;
      if(f){
        const float* Af = (const float*)A;
        float4 v0 = *(const float4*)(Af+off);
        float4 v1 = *(const float4*)(Af+off+4);
        u16 tmp[8];
        tmp[0]=f2bf(v0.x); tmp[1]=f2bf(v0.y); tmp[2]=f2bf(v0.z); tmp[3]=f2bf(v0.w);
        tmp[4]=f2bf(v1.x); tmp[5]=f2bf(v1.y); tmp[6]=f2bf(v1.z); tmp[7]=f2bf(v1.w);
        *(uint4*)&As[sm][sk] = *(const uint4*)tmp;
      } else {
        *(uint4*)&As[sm][sk] = *(const uint4*)((const u16*)A + off);
      }
    }
    {
      u32x4 v = {0u,0u,0u,0u};
      if(bok){
        const u32x4* src = (const u32x4*)(Bp + (size_t)(n0+sm)*ldB + kk + sk);
        v = ntB ? __builtin_nontemporal_load(src) : *src;
      }
      *(u32x4*)&Bs[sm][sk] = v;
    }
    __syncthreads();
    bf16x8 a  = *(const bf16x8*)&As[w*16 + lm][lq*8];
    bf16x8 b0 = *(const bf16x8*)&Bs[ 0 + lm][lq*8];
    bf16x8 b1 = *(const bf16x8*)&Bs[16 + lm][lq*8];
    bf16x8 b2 = *(const bf16x8*)&Bs[32 + lm][lq*8];
    bf16x8 b3 = *(const bf16x8*)&Bs[48 + lm][lq*8];
    acc0 = __builtin_amdgcn_mfma_f32_16x16x32_bf16(a, b0, acc0, 0,0,0);
    acc1 = __builtin_amdgcn_mfma_f32_16x16x32_bf16(a, b1, acc1, 0,0,0);
    acc2 = __builtin_amdgcn_mfma_f32_16x16x32_bf16(a, b2, acc2, 0,0,0);
    acc3 = __builtin_amdgcn_mfma_f32_16x16x32_bf16(a, b3, acc3, 0,0,0);
    __syncthreads();
  }
  f32x4 aa[4] = {acc0, acc1, acc2, acc3};
  int mloc = w*16 + lq*4;
  u16* Cp16 = (u16*)C + (size_t)zm*sC + (size_t)zd*sC2;
  float* Cpf = (float*)C + (size_t)zm*sC + (size_t)zd*sC2;
  #pragma unroll
  for(int nb=0;nb<4;nb++){
    if(n0 + nb*16 >= N) break;
    int n = n0 + nb*16 + lm;
    #pragma unroll
    for(int r=0;r<4;r++){
      int m = m0 + mloc + r;
      float v = aa[nb][r];
      if(addB) v += ldx(bias, (long)zm*sBias + m, f);
      if(outF32){
        if(splitK > 1) atomicAdd(&Cpf[(size_t)m*N + n], v);
        else           Cpf[(size_t)m*N + n] = v;
      } else {
        Cp16[(size_t)m*N + n] = f2bf(v);
      }
    }
  }
}

// ======================= GN =======================
__global__ __launch_bounds__(256) void gn_stats_k(const void* x, float* __restrict__ st, int HW,
                                                  int srcF32){
  int g = blockIdx.x, b = blockIdx.y, t = threadIdx.x;
  size_t base = (size_t)(b*512 + g*16)*HW;
  float s=0.f, ss=0.f;
  if(srcF32){
    const float4* xv = (const float4*)((const float*)x + base);
    int tot4 = 16*HW/4;
    for(int e=t; e<tot4; e+=256){
      float4 v = xv[e];
      s += v.x+v.y+v.z+v.w;
      ss += v.x*v.x+v.y*v.y+v.z*v.z+v.w*v.w;
    }
  } else {
    const uint4* xv = (const uint4*)((const u16*)x + base);
    int tot8 = 16*HW/8;
    for(int e=t; e<tot8; e+=256){
      uint4 v = xv[e];
      float fv[8]; unpk8(v, fv);
      #pragma unroll
      for(int j=0;j<8;j++){ s += fv[j]; ss += fv[j]*fv[j]; }
    }
  }
  __shared__ float rs[256], rq[256];
  rs[t]=s; rq[t]=ss; __syncthreads();
  for(int o=128;o>0;o>>=1){ if(t<o){ rs[t]+=rs[t+o]; rq[t]+=rq[t+o]; } __syncthreads(); }
  if(t==0){
    float tot = 16.f*(float)HW;
    float m = rs[0]/tot;
    float var = fmaxf(rq[0]/tot - m*m, 0.f);
    st[(b*32+g)*2]   = m;
    st[(b*32+g)*2+1] = rsqrtf(var + 1e-5f);
  }
}

__global__ __launch_bounds__(256) void gn_aff_k(const void* x, const float* __restrict__ st,
                                                const void* w, const void* bb,
                                                const u16* __restrict__ res, void* outp, int HW,
                                                const int* df, int finalOut, int srcF32){
  int f = *df;
  int id = blockIdx.x*256 + threadIdx.x;
  int tot8 = 4*512*HW/8;
  if(id>=tot8) return;
  size_t e = (size_t)id*8;
  int r = (int)(e / HW);
  int c = r % 512; int b = r / 512;
  int g = c>>4;
  float mean = st[(b*32+g)*2], rstd = st[(b*32+g)*2+1];
  float sw = ldx(w,c,f)*rstd;
  float sb = ldx(bb,c,f) - mean*sw;
  float fv[8];
  if(srcF32){
    float4 a0 = ((const float4*)x)[id*2];
    float4 a1 = ((const float4*)x)[id*2+1];
    fv[0]=a0.x; fv[1]=a0.y; fv[2]=a0.z; fv[3]=a0.w;
    fv[4]=a1.x; fv[5]=a1.y; fv[6]=a1.z; fv[7]=a1.w;
  } else {
    uint4 rv = *(const uint4*)((const u16*)x + e);
    unpk8(rv, fv);
  }
  float o[8];
  #pragma unroll
  for(int j=0;j<8;j++) o[j] = fv[j]*sw + sb;
  if(res){
    uint4 rr = *(const uint4*)(res + e);
    float fr[8]; unpk8(rr, fr);
    #pragma unroll
    for(int j=0;j<8;j++) o[j] += fr[j];
  }
  if(finalOut && f){
    float* o32 = (float*)outp;
    #pragma unroll
    for(int j=0;j<8;j++) o32[e+j] = o[j];
  } else {
    u16 tmp[8];
    #pragma unroll
    for(int j=0;j<8;j++) tmp[j] = f2bf(o[j]);
    *(uint4*)((u16*)outp + e) = *(const uint4*)tmp;
  }
}

// fused single-pass GN for f32 source, HW=784: stats + affine (+res/final)
__global__ __launch_bounds__(256) void gn_f784_k(const float* __restrict__ x,
    const void* w, const void* bb, const u16* __restrict__ res, void* outp,
    const int* df, int finalOut){
  __shared__ float D[12544];
  __shared__ float rs[256], rq[256];
  __shared__ float stat[2];
  int g = blockIdx.x, b = blockIdx.y, t = threadIdx.x;
  int f = *df;
  size_t base = (size_t)(b*512 + g*16)*784;
  const float4* xv = (const float4*)(x + base);
  float s=0.f, ss=0.f;
  for(int e=t; e<3136; e+=256){
    float4 v = xv[e];
    *(float4*)&D[e*4] = v;
    s += v.x+v.y+v.z+v.w;
    ss += v.x*v.x+v.y*v.y+v.z*v.z+v.w*v.w;
  }
  rs[t]=s; rq[t]=ss; __syncthreads();
  for(int o=128;o>0;o>>=1){ if(t<o){ rs[t]+=rs[t+o]; rq[t]+=rq[t+o]; } __syncthreads(); }
  if(t==0){
    float m = rs[0]/12544.f;
    float var = fmaxf(rq[0]/12544.f - m*m, 0.f);
    stat[0]=m; stat[1]=rsqrtf(var + 1e-5f);
  }
  __syncthreads();
  float mean = stat[0], rstd = stat[1];
  for(int e=t; e<3136; e+=256){
    int c = g*16 + e/196;
    float sw = ldx(w, c, f)*rstd;
    float sb = ldx(bb, c, f) - mean*sw;
    float4 v = *(const float4*)&D[e*4];
    float o4[4] = {v.x*sw+sb, v.y*sw+sb, v.z*sw+sb, v.w*sw+sb};
    if(res){
      uint2 rr = *(const uint2*)(res + base + e*4);
      o4[0] += __uint_as_float(rr.x<<16);
      o4[1] += __uint_as_float(rr.x&0xFFFF0000u);
      o4[2] += __uint_as_float(rr.y<<16);
      o4[3] += __uint_as_float(rr.y&0xFFFF0000u);
    }
    if(finalOut && f){
      *(float4*)((float*)outp + base + e*4) = (float4){o4[0],o4[1],o4[2],o4[3]};
    } else {
      u16 tmp[4];
      #pragma unroll
      for(int j=0;j<4;j++) tmp[j] = f2bf(o4[j]);
      *(uint2*)((u16*)outp + base + e*4) = *(const uint2*)tmp;
    }
  }
}

__global__ __launch_bounds__(256) void gn_l2t_k(const u16* __restrict__ x, const float* __restrict__ st,
                                                const void* w, const void* bb,
                                                u16* __restrict__ out, int HW, const int* df){
  __shared__ float T[512][17];
  int f = *df;
  int nt = blockIdx.x, b = blockIdx.y, t = threadIdx.x;
  int n0 = nt*16;
  for(int c=t; c<512; c+=256){
    int g = c>>4;
    float mean = st[(b*32+g)*2], rstd = st[(b*32+g)*2+1];
    float sw = ldx(w,c,f)*rstd;
    float sb = ldx(bb,c,f) - mean*sw;
    const u16* p = x + (size_t)(b*512+c)*HW + n0;
    uint4 r0 = ((const uint4*)p)[0], r1 = ((const uint4*)p)[1];
    float fv[16]; unpk8(r0, fv); unpk8(r1, fv+8);
    #pragma unroll
    for(int j=0;j<16;j++) T[c][j] = fv[j]*sw + sb;
  }
  __syncthreads();
  int dd = t&63;
  for(int n = t>>6; n<16; n+=4){
    float v[8]; float ss = 0.f;
    #pragma unroll
    for(int h=0;h<8;h++){ v[h] = T[h*64+dd][n]; ss += v[h]*v[h]; }
    float rn = 1.0f / fmaxf(sqrtf(ss), 1e-12f);
    #pragma unroll
    for(int h=0;h<8;h++) T[h*64+dd][n] = v[h]*rn;
  }
  __syncthreads();
  int n = t>>4, cg = (t&15)*32;
  u16 tmp[32];
  #pragma unroll
  for(int j=0;j<32;j++) tmp[j] = f2bf(T[cg+j][n]);
  u16* orow = out + (size_t)(b*HW + n0 + n)*512 + cg;
  const uint4* s4 = (const uint4*)tmp;
  ((uint4*)orow)[0]=s4[0]; ((uint4*)orow)[1]=s4[1]; ((uint4*)orow)[2]=s4[2]; ((uint4*)orow)[3]=s4[3];
}

__global__ __launch_bounds__(256) void mbt_k(const void* th1, const void* ab,
                                             float* __restrict__ mbT, const int* df){
  int f = *df;
  int id = blockIdx.x*256 + threadIdx.x;
  if(id >= 3136*8) return;
  int o = id & 7; int idx = id >> 3;
  float s = 0.f;
  #pragma unroll
  for(int i=0;i<8;i++) s += ldx(th1, o*8+i, f) * ldx(ab, (long)i*3136+idx, f);
  mbT[id] = s;
}

// ======================= attention (fused, P-free) =======================
// qmix[(b*8+o)][q][c] = qnt[b][q][c] * th1[o][c>>6] * 0.125  (th1 premix)
__global__ __launch_bounds__(256) void qmix_k(const u16* __restrict__ qnt,
    const void* th1w, u16* __restrict__ qmix, const int* df){
  int f = *df;
  int id = blockIdx.x*256 + threadIdx.x;
  if(id >= 1605632) return;             // 32*784*512/8
  size_t e = (size_t)id*8;
  int c = (int)(e & 511);
  int row = (int)(e >> 9);
  int q = row % 784;
  int ob = row / 784;                   // b*8 + o
  int o = ob & 7, b = ob >> 3;
  float s1 = ldx(th1w, o*8 + (c>>6), f) * 0.125f;
  uint4 v = *(const uint4*)(qnt + ((size_t)b*784 + q)*512 + c);
  float fv[8]; unpk8(v, fv);
  u16 tmp[8];
  #pragma unroll
  for(int j=0;j<8;j++) tmp[j] = f2bf(fv[j]*s1);
  *(uint4*)(qmix + e) = *(const uint4*)tmp;
}

// Block = (64q-tile x output-head o [blockIdx.x = qt*8+o], n-quarter, b).
// s_o(q,n) = qmix_o(q,:)·kn(n,:) over K=512 — no per-n VALU mix (premixed).
// Per 32n chunk: coop-stage K into swizzled LDS (round-7 pattern), 4-chain
// MFMA QK (round-6), exp+bias -> per-wave Ps tile, PV via MFMA with V from
// global (round-5 pattern). Unnormalized U->obuf atomics + l->lbuf atomics;
// th2/l applied by mix_k. Eliminates the 315MB P materialization.
__global__ __launch_bounds__(256) void attn2_k(const u16* __restrict__ qmix,
    const u16* __restrict__ knt, const u16* __restrict__ vmap,
    const float* __restrict__ mbT, float* __restrict__ lout,
    float* __restrict__ obuf){
  __shared__ u16 Ks[32*520];           // 32n x 512c, pad 520, XOR-swz 16B units
  __shared__ u16 Ps[4][16*40];         // per-wave 16q x 32n P tile
  int qt = blockIdx.x >> 3, o = blockIdx.x & 7;
  int b = blockIdx.z;
  int c0 = blockIdx.y*25, c1 = min(98, c0+25);
  int t = threadIdx.x, w = t>>6, l = t&63, lm = l&15, lq = l>>4;
  int qw = qt*64 + w*16;               // wave's q base
  int qlr = qw + lm; if(qlr > 783) qlr = 783;
  const u16* qrow = qmix + ((size_t)(b*8+o)*784 + qlr)*512;
  bf16x8 qa[16];
  #pragma unroll
  for(int i2=0;i2<16;i2++) qa[i2] = *(const bf16x8*)(qrow + i2*32 + lq*8);
  int qy2[4], qx2[4]; bool qv[4];
  #pragma unroll
  for(int r=0;r<4;r++){
    int qg = qw + lq*4 + r;
    qv[r] = qg < 784;
    if(qg > 783) qg = 783;
    qy2[r] = 2*(qg/28); qx2[r] = 2*(qg%28);
  }
  f32x4 outa[4];
  #pragma unroll
  for(int i=0;i<4;i++) outa[i] = (f32x4){0.f,0.f,0.f,0.f};
  float lacc[4] = {0.f,0.f,0.f,0.f};
  u16* Psw = &Ps[w][0];
  const u16* kbase0 = knt + (size_t)b*3136*512;

  for(int ch=c0; ch<c1; ch++){
    int n0 = ch*32;
    {   // coop K stage (32 rows x 512 ch), swizzled (round-7 verbatim)
      const u16* kbase = kbase0 + (size_t)n0*512;
      uint4* Ks4 = (uint4*)Ks;
      #pragma unroll
      for(int j=0;j<8;j++){
        int idx = t + j*256;
        int row = idx>>6, col = idx&63;
        Ks4[row*65 + (col ^ (row&7))] = *(const uint4*)(kbase + (size_t)row*512 + col*8);
      }
    }
    __syncthreads();                   // Ks ready
    #pragma unroll
    for(int st=0; st<2; st++){
      int row = st*16 + lm;
      const u16* kr = Ks + row*520;
      int sw = row & 7;
      f32x4 d0={0.f,0.f,0.f,0.f}, d1=d0, d2=d0, d3=d0;
      #pragma unroll
      for(int g=0; g<4; g++){
        bf16x8 k0 = *(const bf16x8*)(kr + (size_t)((((g*4+0)*4)+lq)^sw)*8);
        bf16x8 k1 = *(const bf16x8*)(kr + (size_t)((((g*4+1)*4)+lq)^sw)*8);
        bf16x8 k2 = *(const bf16x8*)(kr + (size_t)((((g*4+2)*4)+lq)^sw)*8);
        bf16x8 k3 = *(const bf16x8*)(kr + (size_t)((((g*4+3)*4)+lq)^sw)*8);
        d0 = __builtin_amdgcn_mfma_f32_16x16x32_bf16(qa[g*4+0], k0, d0, 0,0,0);
        d1 = __builtin_amdgcn_mfma_f32_16x16x32_bf16(qa[g*4+1], k1, d1, 0,0,0);
        d2 = __builtin_amdgcn_mfma_f32_16x16x32_bf16(qa[g*4+2], k2, d2, 0,0,0);
        d3 = __builtin_amdgcn_mfma_f32_16x16x32_bf16(qa[g*4+3], k3, d3, 0,0,0);
      }
      f32x4 dt = (d0+d1)+(d2+d3);
      int ng = n0 + row;
      int ny = ng/56, nx = ng%56;
      #pragma unroll
      for(int r=0;r<4;r++){
        int idx = iabs(qy2[r]-ny)*56 + iabs(qx2[r]-nx);
        float p = qv[r] ? __expf(fminf(dt[r] + mbT[idx*8+o], 60.f)) : 0.f;
        lacc[r] += p;
        Psw[(lq*4+r)*40 + st*16 + lm] = f2bf(p);
      }
    }
    // PV (same-wave Ps; compiler lgkmcnt orders the RAW)
    bf16x8 pf = *(const bf16x8*)&Psw[lm*40 + lq*8];
    #pragma unroll
    for(int ct=0;ct<4;ct++){
      int c = o*64 + ct*16 + lm;
      bf16x8 vb = *(const bf16x8*)(vmap + ((size_t)b*512 + c)*3136 + n0 + lq*8);
      outa[ct] = __builtin_amdgcn_mfma_f32_16x16x32_bf16(pf, vb, outa[ct], 0,0,0);
    }
    __syncthreads();                   // all waves done with Ks before restage
  }
  // l: sum over the 16 n-lanes (lm)
  #pragma unroll
  for(int r=0;r<4;r++){
    float v = lacc[r];
    v += __shfl_xor(v,1); v += __shfl_xor(v,2);
    v += __shfl_xor(v,4); v += __shfl_xor(v,8);
    if(lm==0 && qv[r]) atomicAdd(&lout[((size_t)b*8+o)*784 + qw + lq*4 + r], v);
  }
  // unnormalized U (head o's 64 channels)
  #pragma unroll
  for(int ct=0;ct<4;ct++){
    int c = o*64 + ct*16 + lm;
    float* op = obuf + ((size_t)b*512+c)*784 + qw + lq*4;
    #pragma unroll
    for(int r=0;r<4;r++)
      if(qv[r]) atomicAdd(op+r, outa[ct][r]);
  }
}

// epilogue: obuf[c=oo*64+d][q] = sum_o th2[oo,o] * U[o*64+d][q] / l[o][q]
__global__ __launch_bounds__(256) void mix_k(float* __restrict__ obuf,
    const float* __restrict__ lbuf, const void* th2w, const int* df){
  int f = *df;
  __shared__ float T2[64];
  if(threadIdx.x < 64) T2[threadIdx.x] = ldx(th2w, threadIdx.x, f);
  __syncthreads();
  int id = blockIdx.x*256 + threadIdx.x;   // 4*64*784 total
  int q = id % 784;
  int r = id / 784;
  int d = r & 63;
  int b = r >> 6;
  float un[8];
  #pragma unroll
  for(int o=0;o<8;o++){
    float u = obuf[((size_t)(b*512) + o*64 + d)*784 + q];
    float lv = lbuf[((size_t)b*8+o)*784 + q];
    un[o] = (lv > 0.f) ? u / lv : 0.f;
  }
  #pragma unroll
  for(int oo=0;oo<8;oo++){
    float s = 0.f;
    #pragma unroll
    for(int o=0;o<8;o++) s += T2[oo*8+o]*un[o];
    obuf[((size_t)(b*512) + oo*64 + d)*784 + q] = s;
  }
}

// ---------------------------------------------------------------------------
extern "C" void kernel_launch(void* const* d_in, const int* in_sizes, int n_in,
                              void* d_out, int out_size, void* d_ws, size_t ws_size,
                              hipStream_t stream){
  u16* out16 = (u16*)d_out;

  if(n_in != 28){ sentinel_k<<<dim3(1),64,0,stream>>>(out16, 90112.f); return; }
  if(in_sizes[0]  != 3211264){ sentinel_k<<<dim3(1),64,0,stream>>>(out16, 88064.f); return; }
  if(in_sizes[22] != 1179648){ sentinel_k<<<dim3(1),64,0,stream>>>(out16, 81920.f); return; }
  if(out_size != 1605632){ sentinel_k<<<dim3(1),64,0,stream>>>(out16, 75776.f); return; }

  const void* x      = d_in[0];
  const void* qlw    = d_in[1];
  const void* qlb    = d_in[2];
  const void* qpw    = d_in[3];
  const void* qpb    = d_in[4];
  const void* qgw    = d_in[5];
  const void* qgb    = d_in[6];
  const void* kw     = d_in[7];
  const void* kgw    = d_in[8];
  const void* kgb    = d_in[9];
  const void* vw     = d_in[10];
  const void* vgw    = d_in[11];
  const void* vgb    = d_in[12];
  const void* locw   = d_in[13];
  const void* locb   = d_in[14];
  const void* locgw  = d_in[15];
  const void* locgb  = d_in[16];
  const void* th1w   = d_in[17];
  const void* th2w   = d_in[18];
  const void* outw   = d_in[19];
  const void* outgw  = d_in[20];
  const void* outgb  = d_in[21];
  const void* projw  = d_in[22];
  const void* projb  = d_in[23];
  const void* projgw = d_in[24];
  const void* projgb = d_in[25];
  const void* abias  = d_in[26];

  char* ws = (char*)d_ws;
  size_t off = 0;
  auto alloc = [&](size_t bytes)->void*{
    void* p = ws + off;
    off += (bytes + 255) & ~(size_t)255;
    return p;
  };
  const size_t SM_SMALL = (size_t)4*512*784*2;    // 3.21 MB
  const size_t SM_BIG   = (size_t)4*512*3136*2;   // 12.85 MB
  u16* arenaB  = (u16*)alloc(SM_BIG);             // kpre -> vpre
  u16* arenaC  = (u16*)alloc(SM_SMALL);           // qpre -> hbufT
  u16* colArena= (u16*)alloc((size_t)4*784*4608*2); // 28.9 MB: proj col -> tbufT -> loc col -> obuf
  u16* arenaX  = (u16*)alloc(SM_BIG);             // xT -> vmap
  u16* xproj   = (u16*)alloc(SM_SMALL);
  u16* qnt     = (u16*)alloc(SM_SMALL);
  u16* knt     = (u16*)alloc(SM_BIG);
  u16* vloc    = (u16*)alloc(SM_SMALL);
  float* mbT   = (float*)alloc((size_t)3136*8*4);
  float* lbuf  = (float*)alloc((size_t)4*8*784*4);
  int*   dflag = (int*)alloc(256);
  float* st1   = (float*)alloc(4*32*2*4);
  float* st2   = (float*)alloc(4*32*2*4);
  float* st3   = (float*)alloc(4*32*2*4);
  float* preF32= (float*)alloc((size_t)4*512*784*4);  // 6.42 MB splitK scratch
  u16* qmixbuf = (u16*)alloc((size_t)32*784*512*2);   // 25.7 MB th1-premixed Q

  if(off > ws_size){
    float code = 100000.f + (float)(ws_size >> 20) * 100.f;
    sentinel_k<<<dim3(1),64,0,stream>>>(out16, code);
    return;
  }

  u16* qpre    = arenaC;
  u16* hbufT   = arenaC;             // after qpre dead
  u16* kpre    = arenaB;
  u16* vpre    = arenaB;
  u16* xT      = arenaX;
  u16* vmap    = arenaX;             // after xT dead
  u16* tbufT   = colArena;           // after proj col dead
  float* obuf  = (float*)colArena;   // after loc col dead

  detect_k<<<dim3(1),256,0,stream>>>(x, dflag);

  // xT = transpose(x) bf16
  transp_k<<<dim3(98,8,4),256,0,stream>>>(x, xT, dflag);

  // x_proj = GN(conv3x3s2(x, proj_w) + proj_b) — batched, splitK=3, fused GN
  im2col_bt_k<<<dim3(7056,4),256,0,stream>>>(x, (long)256*3136, colArena, 256, 1, dflag);
  zero_k<<<dim3(1024),256,0,stream>>>(preF32, 4L*512*784);
  gemm_mfma_k<<<dim3(13,24,4),256,0,stream>>>(projw, colArena, preF32, projb,
      512,784,2304, 2304, 0,(long)784*2304,(long)512*784,0, 0,0,64, 3, 0, 1, dflag);
  gn_f784_k<<<dim3(32,4),256,0,stream>>>(preF32, projgw, projgb, nullptr, xproj, dflag, 0);

  // q = l2norm(GN(conv1x1(depthwise+pool) + b)) -> [q][c]
  qlocal_bt_k<<<dim3(3136),256,0,stream>>>(x, qlw, qlb, tbufT, dflag);
  gemm_mfma_k<<<dim3(13,8,4),256,0,stream>>>(qpw, tbufT, qpre, qpb,
      512,784,256, 256, 0,(long)784*256,(long)512*784,0, 0,0,64, 1, 0, 0, dflag);
  gn_stats_k<<<dim3(32,4),256,0,stream>>>(qpre, st1, 784, 0);
  gn_l2t_k<<<dim3(49,4),256,0,stream>>>(qpre, st1, qgw, qgb, qnt, 784, dflag);

  // k = l2norm(GN(conv1x1(x))) -> [n][c]
  gemm_mfma_k<<<dim3(49,8,4),256,0,stream>>>(kw, xT, kpre, nullptr,
      512,3136,256, 256, 0,(long)3136*256,(long)512*3136,0, 0,0,64, 1, 0, 0, dflag);
  gn_stats_k<<<dim3(32,4),256,0,stream>>>(kpre, st2, 3136, 0);
  gn_l2t_k<<<dim3(196,4),256,0,stream>>>(kpre, st2, kgw, kgb, knt, 3136, dflag);

  // v_map = GN(conv1x1(x))
  gemm_mfma_k<<<dim3(49,8,4),256,0,stream>>>(vw, xT, vpre, nullptr,
      512,3136,256, 256, 0,(long)3136*256,(long)512*3136,0, 0,0,64, 1, 0, 0, dflag);
  gn_stats_k<<<dim3(32,4),256,0,stream>>>(vpre, st3, 3136, 0);
  gn_aff_k<<<dim3(3136),256,0,stream>>>(vpre, st3, vgw, vgb, nullptr, vmap, 3136, dflag, 0, 0);

  // v_local = GN(groupconv3x3s2(v_map) + loc_b) — batched, splitK=2, fused GN
  im2col_bt_k<<<dim3(14112,4),256,0,stream>>>(vmap, (long)512*3136, colArena, 512, 0, dflag);
  zero_k<<<dim3(1024),256,0,stream>>>(preF32, 4L*512*784);
  gemm_mfma_k<<<dim3(13,2,32),256,0,stream>>>(locw, colArena, preF32, locb,
      64,784,576, 4608, (long)64*576,576,(long)64*784,64,
      (long)784*4608,(long)512*784,8, 2, 0, 1, dflag);
  gn_f784_k<<<dim3(32,4),256,0,stream>>>(preF32, locgw, locgb, nullptr, vloc, dflag, 0);

  // ---- attention: th1 premix, fused P-free QK/PV, then th2/l mix ----
  mbt_k<<<dim3(98),256,0,stream>>>(th1w, abias, mbT, dflag);
  zero_k<<<dim3(32),256,0,stream>>>(lbuf, 4L*8*784);
  zero_k<<<dim3(1024),256,0,stream>>>(obuf, 4L*512*784);
  qmix_k<<<dim3(6272),256,0,stream>>>(qnt, th1w, qmixbuf, dflag);
  attn2_k<<<dim3(104,4,4),256,0,stream>>>(qmixbuf, knt, vmap, mbT, lbuf, obuf);
  mix_k<<<dim3(784),256,0,stream>>>(obuf, lbuf, th2w, dflag);

  // out = GN(conv1x1(hardswish(attn_out + v_local))) + x_proj — splitK=2, fused GN
  hs_addT_k<<<dim3(25,16,4),256,0,stream>>>(obuf, vloc, hbufT);
  zero_k<<<dim3(1024),256,0,stream>>>(preF32, 4L*512*784);
  gemm_mfma_k<<<dim3(13,16,4),256,0,stream>>>(outw, hbufT, preF32, nullptr,
      512,784,512, 512, 0,(long)784*512,(long)512*784,0, 0,0,64, 2, 0, 1, dflag);
  gn_f784_k<<<dim3(32,4),256,0,stream>>>(preF32, outgw, outgb, xproj, d_out, dflag, 1);

  sanitize_k<<<dim3(1024),256,0,stream>>>(d_out, (long)out_size, dflag);
}

// Round 15
// 851.628 us; speedup vs baseline: 1.0349x; 1.0349x over previous
//
#include <hip/hip_runtime.h>
#include <stdint.h>

typedef unsigned short u16;
typedef unsigned int u32;
typedef __attribute__((ext_vector_type(8))) short bf16x8;
typedef __attribute__((ext_vector_type(4))) float f32x4;
typedef __attribute__((ext_vector_type(4))) u32 u32x4;

#define DEV static __device__ __forceinline__

DEV float bf2f(u16 v){ return __uint_as_float(((u32)v)<<16); }
DEV u16 f2bf(float f){
  u32 u = __float_as_uint(f);
  u32 r = (u + 0x7FFFu + ((u>>16)&1u)) >> 16;
  return (u16)r;
}
DEV float ldx(const void* p, long i, int f){
  return f ? ((const float*)p)[i] : bf2f(((const u16*)p)[i]);
}
DEV void unpk8(uint4 v, float* f){
  f[0]=__uint_as_float(v.x<<16); f[1]=__uint_as_float(v.x&0xFFFF0000u);
  f[2]=__uint_as_float(v.y<<16); f[3]=__uint_as_float(v.y&0xFFFF0000u);
  f[4]=__uint_as_float(v.z<<16); f[5]=__uint_as_float(v.z&0xFFFF0000u);
  f[6]=__uint_as_float(v.w<<16); f[7]=__uint_as_float(v.w&0xFFFF0000u);
}
DEV int iabs(int a){ return a<0? -a : a; }

// ======================= dtype probe / guards =======================
__global__ void detect_k(const void* x, int* dflag){
  const u16* p = (const u16*)x;
  int t = threadIdx.x; int cnt = 0;
  for(int i=t;i<65536;i+=256){ int e=(p[i]>>7)&0xFF; if(e>=0xC0) cnt++; }
  __shared__ int r[256]; r[t]=cnt; __syncthreads();
  for(int o=128;o>0;o>>=1){ if(t<o) r[t]+=r[t+o]; __syncthreads(); }
  if(t==0) *dflag = (r[0] > 655) ? 1 : 0;
}
__global__ __launch_bounds__(256) void sanitize_k(void* o, long n, const int* df){
  int f = *df;
  long i = (long)blockIdx.x*256 + threadIdx.x;
  long st = (long)gridDim.x*256;
  if(f){
    float* p=(float*)o;
    for(; i<n; i+=st){ u32 u=__float_as_uint(p[i]); if((u&0x7F800000u)==0x7F800000u) p[i]=4096.f; }
  } else {
    u16* p=(u16*)o;
    u16 c = f2bf(4096.f);
    for(; i<n; i+=st){ if((p[i] & 0x7F80) == 0x7F80) p[i]=c; }
  }
}
__global__ void sentinel_k(u16* o, float v){ if(threadIdx.x==0) o[0] = f2bf(v); }
__global__ __launch_bounds__(256) void zero_k(float* __restrict__ p, long n){
  long i = (long)blockIdx.x*256 + threadIdx.x;
  long st = (long)gridDim.x*256;
  for(; i<n; i+=st) p[i]=0.f;
}

// ======================= data movement =======================
__global__ __launch_bounds__(256) void transp_k(const void* x, u16* __restrict__ xT, const int* df){
  __shared__ float T[32][33];
  int f = *df;
  int p0 = blockIdx.x*32, c0 = blockIdx.y*32, b = blockIdx.z;
  int tx = threadIdx.x & 31, ty = threadIdx.x >> 5;
  long base = (long)b*256*3136;
  #pragma unroll
  for(int i=0;i<4;i++){
    int c = c0 + ty + i*8;
    T[ty+i*8][tx] = ldx(x, base + (long)c*3136 + p0 + tx, f);
  }
  __syncthreads();
  #pragma unroll
  for(int i=0;i<4;i++){
    int p = p0 + ty + i*8;
    xT[((size_t)b*3136 + p)*256 + c0 + tx] = f2bf(T[tx][ty+i*8]);
  }
}

// batched over blockIdx.y = b
__global__ __launch_bounds__(256) void im2col_bt_k(const void* in, long bstride, u16* __restrict__ out,
                                                   int Cin, int isInput, const int* df){
  int f = isInput ? *df : 0;
  int K9 = Cin*9;
  int total = 784*K9;
  int id = blockIdx.x*256 + threadIdx.x;
  if(id>=total) return;
  long off = (long)blockIdx.y * bstride;
  u16* op = out + (size_t)blockIdx.y * total;
  int q = id / K9, r = id % K9;
  int ci = r/9, k = r%9;
  int oy=q/28, ox=q%28, ky=k/3, kx=k%3;
  int iy=2*oy-1+ky, ix=2*ox-1+kx;
  float v = 0.f;
  if((u32)iy<56u && (u32)ix<56u) v = ldx(in, off + (long)ci*3136 + iy*56+ix, f);
  op[id] = f2bf(v);
}

__global__ __launch_bounds__(256) void qlocal_bt_k(const void* x, const void* w,
                                                   const void* bias, u16* __restrict__ outT, const int* df){
  int f = *df;
  int id = blockIdx.x*256 + threadIdx.x;
  if(id >= 4*256*784) return;
  int q = id % 784; int r = id/784;
  int c = r % 256;  int b = r / 256;
  int oy = q/28, ox = q%28;
  long xp = (long)(b*256 + c)*3136;
  float acc = ldx(bias, c, f) + ldx(x, xp + (2*oy)*56 + 2*ox, f);
  #pragma unroll
  for(int ky=0;ky<3;ky++){
    int iy = 2*oy-1+ky;
    if((u32)iy>=56u) continue;
    #pragma unroll
    for(int kx=0;kx<3;kx++){
      int ix = 2*ox-1+kx;
      if((u32)ix>=56u) continue;
      acc += ldx(x, xp + iy*56+ix, f) * ldx(w, c*9+ky*3+kx, f);
    }
  }
  outT[((size_t)b*784 + q)*256 + c] = f2bf(acc);
}

// hardswish(obuf_fp32 + vloc) -> hbufT[b][q][c]
__global__ __launch_bounds__(256) void hs_addT_k(const float* __restrict__ a, const u16* __restrict__ bsrc,
                                                 u16* __restrict__ outT){
  __shared__ float T[32][33];
  int q0 = blockIdx.x*32, c0 = blockIdx.y*32, b = blockIdx.z;
  int tx = threadIdx.x&31, ty = threadIdx.x>>5;
  #pragma unroll
  for(int i=0;i<4;i++){
    int c = c0+ty+i*8;
    int q = q0+tx;
    float s = 0.f;
    if(q < 784){
      size_t e = ((size_t)b*512 + c)*784 + q;
      s = a[e] + bf2f(bsrc[e]);
      float cl = fminf(fmaxf(s+3.f,0.f),6.f);
      s = s*cl*(1.f/6.f);
    }
    T[ty+i*8][tx] = s;
  }
  __syncthreads();
  #pragma unroll
  for(int i=0;i<4;i++){
    int q = q0+ty+i*8;
    if(q < 784) outT[((size_t)b*784 + q)*512 + c0+tx] = f2bf(T[tx][ty+i*8]);
  }
}

// ======================= MFMA GEMM (BT convention) =======================
// z decomposed as zd*zdiv + zm: offsets = zm*s + zd*s2 (A/bias use zm only).
// splitK>1: blockIdx.y = my*splitK + kc; fp32 atomicAdd C writes (outF32
// required); bias added only by kc==0 blocks.
// ntB: non-temporal B loads. outF32: float C (sC/sC2 count floats).
__global__ __launch_bounds__(256) void gemm_mfma_k(const void* A, const u16* __restrict__ BT,
                                                   void* C, const void* bias,
                                                   int M, int N, int K, int ldB,
                                                   long sA, long sB, long sC, int sBias,
                                                   long sB2, long sC2, int zdiv,
                                                   int splitK, int ntB, int outF32, const int* df){
  __shared__ u16 As[64][40];
  __shared__ u16 Bs[64][40];
  int f = *df;
  int z = blockIdx.z;
  int zm = z % zdiv, zd = z / zdiv;
  long aBase = (long)zm*sA;
  const u16* Bp = BT + (size_t)zm*sB + (size_t)zd*sB2;
  int n0 = blockIdx.x*64;
  int m0, kStart, kEnd;
  bool addB;
  if(splitK > 1){
    int my = blockIdx.y / splitK;
    int kc = blockIdx.y % splitK;
    m0 = my*64;
    int kLen = K/splitK;
    kStart = kc*kLen;
    kEnd = kStart + kLen;
    addB = (bias != nullptr) && (kc == 0);
  } else {
    m0 = blockIdx.y*64;
    kStart = 0; kEnd = K;
    addB = (bias != nullptr);
  }
  int t = threadIdx.x;
  int sm = t>>2, sk = (t&3)*8;
  int w = t>>6, l = t&63;
  int lm = l&15, lq = l>>4;
  f32x4 acc0={0.f,0.f,0.f,0.f}, acc1=acc0, acc2=acc0, acc3=acc0;
  bool bok = (n0 + sm) < N;
  for(int kk=kStart; kk<kEnd; kk+=32){
    {
      long off = aBase + (long)(m0+sm)*K + kk + sk;
      if(f){
        const float* Af = (const float*)A;
        float4 v0 = *(const float4*)(Af+off);
        float4 v1 = *(const float4*)(Af+off+4);
        u16 tmp[8];
        tmp[0]=f2bf(v0.x); tmp[1]=f2bf(v0.y); tmp[2]=f2bf(v0.z); tmp[3]=f2bf(v0.w);
        tmp[4]=f2bf(v1.x); tmp[5]=f2bf(v1.y); tmp[6]=f2bf(v1.z); tmp[7]=f2bf(v1.w);
        *(uint4*)&As[sm][sk] = *(const uint4*)tmp;
      } else {
        *(uint4*)&As[sm][sk] = *(const uint4*)((const u16*)A + off);
      }
    }
    {
      u32x4 v = {0u,0u,0u,0u};
      if(bok){
        const u32x4* src = (const u32x4*)(Bp + (size_t)(n0+sm)*ldB + kk + sk);
        v = ntB ? __builtin_nontemporal_load(src) : *src;
      }
      *(u32x4*)&Bs[sm][sk] = v;
    }
    __syncthreads();
    bf16x8 a  = *(const bf16x8*)&As[w*16 + lm][lq*8];
    bf16x8 b0 = *(const bf16x8*)&Bs[ 0 + lm][lq*8];
    bf16x8 b1 = *(const bf16x8*)&Bs[16 + lm][lq*8];
    bf16x8 b2 = *(const bf16x8*)&Bs[32 + lm][lq*8];
    bf16x8 b3 = *(const bf16x8*)&Bs[48 + lm][lq*8];
    acc0 = __builtin_amdgcn_mfma_f32_16x16x32_bf16(a, b0, acc0, 0,0,0);
    acc1 = __builtin_amdgcn_mfma_f32_16x16x32_bf16(a, b1, acc1, 0,0,0);
    acc2 = __builtin_amdgcn_mfma_f32_16x16x32_bf16(a, b2, acc2, 0,0,0);
    acc3 = __builtin_amdgcn_mfma_f32_16x16x32_bf16(a, b3, acc3, 0,0,0);
    __syncthreads();
  }
  f32x4 aa[4] = {acc0, acc1, acc2, acc3};
  int mloc = w*16 + lq*4;
  u16* Cp16 = (u16*)C + (size_t)zm*sC + (size_t)zd*sC2;
  float* Cpf = (float*)C + (size_t)zm*sC + (size_t)zd*sC2;
  #pragma unroll
  for(int nb=0;nb<4;nb++){
    if(n0 + nb*16 >= N) break;
    int n = n0 + nb*16 + lm;
    #pragma unroll
    for(int r=0;r<4;r++){
      int m = m0 + mloc + r;
      float v = aa[nb][r];
      if(addB) v += ldx(bias, (long)zm*sBias + m, f);
      if(outF32){
        if(splitK > 1) atomicAdd(&Cpf[(size_t)m*N + n], v);
        else           Cpf[(size_t)m*N + n] = v;
      } else {
        Cp16[(size_t)m*N + n] = f2bf(v);
      }
    }
  }
}

// ======================= GN =======================
__global__ __launch_bounds__(256) void gn_stats_k(const void* x, float* __restrict__ st, int HW,
                                                  int srcF32){
  int g = blockIdx.x, b = blockIdx.y, t = threadIdx.x;
  size_t base = (size_t)(b*512 + g*16)*HW;
  float s=0.f, ss=0.f;
  if(srcF32){
    const float4* xv = (const float4*)((const float*)x + base);
    int tot4 = 16*HW/4;
    for(int e=t; e<tot4; e+=256){
      float4 v = xv[e];
      s += v.x+v.y+v.z+v.w;
      ss += v.x*v.x+v.y*v.y+v.z*v.z+v.w*v.w;
    }
  } else {
    const uint4* xv = (const uint4*)((const u16*)x + base);
    int tot8 = 16*HW/8;
    for(int e=t; e<tot8; e+=256){
      uint4 v = xv[e];
      float fv[8]; unpk8(v, fv);
      #pragma unroll
      for(int j=0;j<8;j++){ s += fv[j]; ss += fv[j]*fv[j]; }
    }
  }
  __shared__ float rs[256], rq[256];
  rs[t]=s; rq[t]=ss; __syncthreads();
  for(int o=128;o>0;o>>=1){ if(t<o){ rs[t]+=rs[t+o]; rq[t]+=rq[t+o]; } __syncthreads(); }
  if(t==0){
    float tot = 16.f*(float)HW;
    float m = rs[0]/tot;
    float var = fmaxf(rq[0]/tot - m*m, 0.f);
    st[(b*32+g)*2]   = m;
    st[(b*32+g)*2+1] = rsqrtf(var + 1e-5f);
  }
}

__global__ __launch_bounds__(256) void gn_aff_k(const void* x, const float* __restrict__ st,
                                                const void* w, const void* bb,
                                                const u16* __restrict__ res, void* outp, int HW,
                                                const int* df, int finalOut, int srcF32){
  int f = *df;
  int id = blockIdx.x*256 + threadIdx.x;
  int tot8 = 4*512*HW/8;
  if(id>=tot8) return;
  size_t e = (size_t)id*8;
  int r = (int)(e / HW);
  int c = r % 512; int b = r / 512;
  int g = c>>4;
  float mean = st[(b*32+g)*2], rstd = st[(b*32+g)*2+1];
  float sw = ldx(w,c,f)*rstd;
  float sb = ldx(bb,c,f) - mean*sw;
  float fv[8];
  if(srcF32){
    float4 a0 = ((const float4*)x)[id*2];
    float4 a1 = ((const float4*)x)[id*2+1];
    fv[0]=a0.x; fv[1]=a0.y; fv[2]=a0.z; fv[3]=a0.w;
    fv[4]=a1.x; fv[5]=a1.y; fv[6]=a1.z; fv[7]=a1.w;
  } else {
    uint4 rv = *(const uint4*)((const u16*)x + e);
    unpk8(rv, fv);
  }
  float o[8];
  #pragma unroll
  for(int j=0;j<8;j++) o[j] = fv[j]*sw + sb;
  if(res){
    uint4 rr = *(const uint4*)(res + e);
    float fr[8]; unpk8(rr, fr);
    #pragma unroll
    for(int j=0;j<8;j++) o[j] += fr[j];
  }
  if(finalOut && f){
    float* o32 = (float*)outp;
    #pragma unroll
    for(int j=0;j<8;j++) o32[e+j] = o[j];
  } else {
    u16 tmp[8];
    #pragma unroll
    for(int j=0;j<8;j++) tmp[j] = f2bf(o[j]);
    *(uint4*)((u16*)outp + e) = *(const uint4*)tmp;
  }
}

// fused single-pass GN for f32 source, HW=784: stats + affine (+res/final)
__global__ __launch_bounds__(256) void gn_f784_k(const float* __restrict__ x,
    const void* w, const void* bb, const u16* __restrict__ res, void* outp,
    const int* df, int finalOut){
  __shared__ float D[12544];
  __shared__ float rs[256], rq[256];
  __shared__ float stat[2];
  int g = blockIdx.x, b = blockIdx.y, t = threadIdx.x;
  int f = *df;
  size_t base = (size_t)(b*512 + g*16)*784;
  const float4* xv = (const float4*)(x + base);
  float s=0.f, ss=0.f;
  for(int e=t; e<3136; e+=256){
    float4 v = xv[e];
    *(float4*)&D[e*4] = v;
    s += v.x+v.y+v.z+v.w;
    ss += v.x*v.x+v.y*v.y+v.z*v.z+v.w*v.w;
  }
  rs[t]=s; rq[t]=ss; __syncthreads();
  for(int o=128;o>0;o>>=1){ if(t<o){ rs[t]+=rs[t+o]; rq[t]+=rq[t+o]; } __syncthreads(); }
  if(t==0){
    float m = rs[0]/12544.f;
    float var = fmaxf(rq[0]/12544.f - m*m, 0.f);
    stat[0]=m; stat[1]=rsqrtf(var + 1e-5f);
  }
  __syncthreads();
  float mean = stat[0], rstd = stat[1];
  for(int e=t; e<3136; e+=256){
    int c = g*16 + e/196;
    float sw = ldx(w, c, f)*rstd;
    float sb = ldx(bb, c, f) - mean*sw;
    float4 v = *(const float4*)&D[e*4];
    float o4[4] = {v.x*sw+sb, v.y*sw+sb, v.z*sw+sb, v.w*sw+sb};
    if(res){
      uint2 rr = *(const uint2*)(res + base + e*4);
      o4[0] += __uint_as_float(rr.x<<16);
      o4[1] += __uint_as_float(rr.x&0xFFFF0000u);
      o4[2] += __uint_as_float(rr.y<<16);
      o4[3] += __uint_as_float(rr.y&0xFFFF0000u);
    }
    if(finalOut && f){
      *(float4*)((float*)outp + base + e*4) = (float4){o4[0],o4[1],o4[2],o4[3]};
    } else {
      u16 tmp[4];
      #pragma unroll
      for(int j=0;j<4;j++) tmp[j] = f2bf(o4[j]);
      *(uint2*)((u16*)outp + base + e*4) = *(const uint2*)tmp;
    }
  }
}

__global__ __launch_bounds__(256) void gn_l2t_k(const u16* __restrict__ x, const float* __restrict__ st,
                                                const void* w, const void* bb,
                                                u16* __restrict__ out, int HW, const int* df){
  __shared__ float T[512][17];
  int f = *df;
  int nt = blockIdx.x, b = blockIdx.y, t = threadIdx.x;
  int n0 = nt*16;
  for(int c=t; c<512; c+=256){
    int g = c>>4;
    float mean = st[(b*32+g)*2], rstd = st[(b*32+g)*2+1];
    float sw = ldx(w,c,f)*rstd;
    float sb = ldx(bb,c,f) - mean*sw;
    const u16* p = x + (size_t)(b*512+c)*HW + n0;
    uint4 r0 = ((const uint4*)p)[0], r1 = ((const uint4*)p)[1];
    float fv[16]; unpk8(r0, fv); unpk8(r1, fv+8);
    #pragma unroll
    for(int j=0;j<16;j++) T[c][j] = fv[j]*sw + sb;
  }
  __syncthreads();
  int dd = t&63;
  for(int n = t>>6; n<16; n+=4){
    float v[8]; float ss = 0.f;
    #pragma unroll
    for(int h=0;h<8;h++){ v[h] = T[h*64+dd][n]; ss += v[h]*v[h]; }
    float rn = 1.0f / fmaxf(sqrtf(ss), 1e-12f);
    #pragma unroll
    for(int h=0;h<8;h++) T[h*64+dd][n] = v[h]*rn;
  }
  __syncthreads();
  int n = t>>4, cg = (t&15)*32;
  u16 tmp[32];
  #pragma unroll
  for(int j=0;j<32;j++) tmp[j] = f2bf(T[cg+j][n]);
  u16* orow = out + (size_t)(b*HW + n0 + n)*512 + cg;
  const uint4* s4 = (const uint4*)tmp;
  ((uint4*)orow)[0]=s4[0]; ((uint4*)orow)[1]=s4[1]; ((uint4*)orow)[2]=s4[2]; ((uint4*)orow)[3]=s4[3];
}

__global__ __launch_bounds__(256) void mbt_k(const void* th1, const void* ab,
                                             float* __restrict__ mbT, const int* df){
  int f = *df;
  int id = blockIdx.x*256 + threadIdx.x;
  if(id >= 3136*8) return;
  int o = id & 7; int idx = id >> 3;
  float s = 0.f;
  #pragma unroll
  for(int i=0;i<8;i++) s += ldx(th1, o*8+i, f) * ldx(ab, (long)i*3136+idx, f);
  mbT[id] = s;
}

// ======================= attention (fused, P-free) =======================
// qmix[(b*8+o)][q][c] = qnt[b][q][c] * th1[o][c>>6] * 0.125  (th1 premix)
__global__ __launch_bounds__(256) void qmix_k(const u16* __restrict__ qnt,
    const void* th1w, u16* __restrict__ qmix, const int* df){
  int f = *df;
  int id = blockIdx.x*256 + threadIdx.x;
  if(id >= 1605632) return;             // 32*784*512/8
  size_t e = (size_t)id*8;
  int c = (int)(e & 511);
  int row = (int)(e >> 9);
  int q = row % 784;
  int ob = row / 784;                   // b*8 + o
  int o = ob & 7, b = ob >> 3;
  float s1 = ldx(th1w, o*8 + (c>>6), f) * 0.125f;
  uint4 v = *(const uint4*)(qnt + ((size_t)b*784 + q)*512 + c);
  float fv[8]; unpk8(v, fv);
  u16 tmp[8];
  #pragma unroll
  for(int j=0;j<8;j++) tmp[j] = f2bf(fv[j]*s1);
  *(uint4*)(qmix + e) = *(const uint4*)tmp;
}

// Block = (64q-tile x output-head o [blockIdx.x = qt*8+o], n-quarter, b).
// s_o(q,n) = qmix_o(q,:)·kn(n,:) over K=512 — no per-n VALU mix (premixed).
// Per 32n chunk: coop-stage K into LDS [32][520] (row stride 65 16B-units
// == 1 mod 8 gives natural bank rotation — the round-14 XOR swizzle was
// ANTI-productive, 73.7M conflict cycles; removed), 4-chain MFMA QK,
// exp+bias -> per-wave Ps tile, PV via MFMA with V from global.
// Unnormalized U->obuf atomics + l->lbuf atomics; th2/l applied by mix_k.
__global__ __launch_bounds__(256) void attn2_k(const u16* __restrict__ qmix,
    const u16* __restrict__ knt, const u16* __restrict__ vmap,
    const float* __restrict__ mbT, float* __restrict__ lout,
    float* __restrict__ obuf){
  __shared__ u16 Ks[32*520];           // 32n x 512c, pad 520 (65 16B-units/row)
  __shared__ u16 Ps[4][16*40];         // per-wave 16q x 32n P tile
  int qt = blockIdx.x >> 3, o = blockIdx.x & 7;
  int b = blockIdx.z;
  int c0 = blockIdx.y*25, c1 = min(98, c0+25);
  int t = threadIdx.x, w = t>>6, l = t&63, lm = l&15, lq = l>>4;
  int qw = qt*64 + w*16;               // wave's q base
  int qlr = qw + lm; if(qlr > 783) qlr = 783;
  const u16* qrow = qmix + ((size_t)(b*8+o)*784 + qlr)*512;
  bf16x8 qa[16];
  #pragma unroll
  for(int i2=0;i2<16;i2++) qa[i2] = *(const bf16x8*)(qrow + i2*32 + lq*8);
  int qy2[4], qx2[4]; bool qv[4];
  #pragma unroll
  for(int r=0;r<4;r++){
    int qg = qw + lq*4 + r;
    qv[r] = qg < 784;
    if(qg > 783) qg = 783;
    qy2[r] = 2*(qg/28); qx2[r] = 2*(qg%28);
  }
  f32x4 outa[4];
  #pragma unroll
  for(int i=0;i<4;i++) outa[i] = (f32x4){0.f,0.f,0.f,0.f};
  float lacc[4] = {0.f,0.f,0.f,0.f};
  u16* Psw = &Ps[w][0];
  const u16* kbase0 = knt + (size_t)b*3136*512;

  for(int ch=c0; ch<c1; ch++){
    int n0 = ch*32;
    {   // coop K stage (32 rows x 512 ch), linear (pad provides rotation)
      const u16* kbase = kbase0 + (size_t)n0*512;
      uint4* Ks4 = (uint4*)Ks;
      #pragma unroll
      for(int j=0;j<8;j++){
        int idx = t + j*256;
        int row = idx>>6, col = idx&63;
        Ks4[row*65 + col] = *(const uint4*)(kbase + (size_t)row*512 + col*8);
      }
    }
    __syncthreads();                   // Ks ready
    #pragma unroll
    for(int st=0; st<2; st++){
      int row = st*16 + lm;
      const u16* kr = Ks + row*520;
      f32x4 d0={0.f,0.f,0.f,0.f}, d1=d0, d2=d0, d3=d0;
      #pragma unroll
      for(int g=0; g<4; g++){
        bf16x8 k0 = *(const bf16x8*)(kr + (size_t)(g*16+ 0+lq)*8);
        bf16x8 k1 = *(const bf16x8*)(kr + (size_t)(g*16+ 4+lq)*8);
        bf16x8 k2 = *(const bf16x8*)(kr + (size_t)(g*16+ 8+lq)*8);
        bf16x8 k3 = *(const bf16x8*)(kr + (size_t)(g*16+12+lq)*8);
        d0 = __builtin_amdgcn_mfma_f32_16x16x32_bf16(qa[g*4+0], k0, d0, 0,0,0);
        d1 = __builtin_amdgcn_mfma_f32_16x16x32_bf16(qa[g*4+1], k1, d1, 0,0,0);
        d2 = __builtin_amdgcn_mfma_f32_16x16x32_bf16(qa[g*4+2], k2, d2, 0,0,0);
        d3 = __builtin_amdgcn_mfma_f32_16x16x32_bf16(qa[g*4+3], k3, d3, 0,0,0);
      }
      f32x4 dt = (d0+d1)+(d2+d3);
      int ng = n0 + row;
      int ny = ng/56, nx = ng%56;
      #pragma unroll
      for(int r=0;r<4;r++){
        int idx = iabs(qy2[r]-ny)*56 + iabs(qx2[r]-nx);
        float p = qv[r] ? __expf(fminf(dt[r] + mbT[idx*8+o], 60.f)) : 0.f;
        lacc[r] += p;
        Psw[(lq*4+r)*40 + st*16 + lm] = f2bf(p);
      }
    }
    // PV (same-wave Ps; compiler lgkmcnt orders the RAW)
    bf16x8 pf = *(const bf16x8*)&Psw[lm*40 + lq*8];
    #pragma unroll
    for(int ct=0;ct<4;ct++){
      int c = o*64 + ct*16 + lm;
      bf16x8 vb = *(const bf16x8*)(vmap + ((size_t)b*512 + c)*3136 + n0 + lq*8);
      outa[ct] = __builtin_amdgcn_mfma_f32_16x16x32_bf16(pf, vb, outa[ct], 0,0,0);
    }
    __syncthreads();                   // all waves done with Ks before restage
  }
  // l: sum over the 16 n-lanes (lm)
  #pragma unroll
  for(int r=0;r<4;r++){
    float v = lacc[r];
    v += __shfl_xor(v,1); v += __shfl_xor(v,2);
    v += __shfl_xor(v,4); v += __shfl_xor(v,8);
    if(lm==0 && qv[r]) atomicAdd(&lout[((size_t)b*8+o)*784 + qw + lq*4 + r], v);
  }
  // unnormalized U (head o's 64 channels)
  #pragma unroll
  for(int ct=0;ct<4;ct++){
    int c = o*64 + ct*16 + lm;
    float* op = obuf + ((size_t)b*512+c)*784 + qw + lq*4;
    #pragma unroll
    for(int r=0;r<4;r++)
      if(qv[r]) atomicAdd(op+r, outa[ct][r]);
  }
}

// epilogue: obuf[c=oo*64+d][q] = sum_o th2[oo,o] * U[o*64+d][q] / l[o][q]
__global__ __launch_bounds__(256) void mix_k(float* __restrict__ obuf,
    const float* __restrict__ lbuf, const void* th2w, const int* df){
  int f = *df;
  __shared__ float T2[64];
  if(threadIdx.x < 64) T2[threadIdx.x] = ldx(th2w, threadIdx.x, f);
  __syncthreads();
  int id = blockIdx.x*256 + threadIdx.x;   // 4*64*784 total
  int q = id % 784;
  int r = id / 784;
  int d = r & 63;
  int b = r >> 6;
  float un[8];
  #pragma unroll
  for(int o=0;o<8;o++){
    float u = obuf[((size_t)(b*512) + o*64 + d)*784 + q];
    float lv = lbuf[((size_t)b*8+o)*784 + q];
    un[o] = (lv > 0.f) ? u / lv : 0.f;
  }
  #pragma unroll
  for(int oo=0;oo<8;oo++){
    float s = 0.f;
    #pragma unroll
    for(int o=0;o<8;o++) s += T2[oo*8+o]*un[o];
    obuf[((size_t)(b*512) + oo*64 + d)*784 + q] = s;
  }
}

// ---------------------------------------------------------------------------
extern "C" void kernel_launch(void* const* d_in, const int* in_sizes, int n_in,
                              void* d_out, int out_size, void* d_ws, size_t ws_size,
                              hipStream_t stream){
  u16* out16 = (u16*)d_out;

  if(n_in != 28){ sentinel_k<<<dim3(1),64,0,stream>>>(out16, 90112.f); return; }
  if(in_sizes[0]  != 3211264){ sentinel_k<<<dim3(1),64,0,stream>>>(out16, 88064.f); return; }
  if(in_sizes[22] != 1179648){ sentinel_k<<<dim3(1),64,0,stream>>>(out16, 81920.f); return; }
  if(out_size != 1605632){ sentinel_k<<<dim3(1),64,0,stream>>>(out16, 75776.f); return; }

  const void* x      = d_in[0];
  const void* qlw    = d_in[1];
  const void* qlb    = d_in[2];
  const void* qpw    = d_in[3];
  const void* qpb    = d_in[4];
  const void* qgw    = d_in[5];
  const void* qgb    = d_in[6];
  const void* kw     = d_in[7];
  const void* kgw    = d_in[8];
  const void* kgb    = d_in[9];
  const void* vw     = d_in[10];
  const void* vgw    = d_in[11];
  const void* vgb    = d_in[12];
  const void* locw   = d_in[13];
  const void* locb   = d_in[14];
  const void* locgw  = d_in[15];
  const void* locgb  = d_in[16];
  const void* th1w   = d_in[17];
  const void* th2w   = d_in[18];
  const void* outw   = d_in[19];
  const void* outgw  = d_in[20];
  const void* outgb  = d_in[21];
  const void* projw  = d_in[22];
  const void* projb  = d_in[23];
  const void* projgw = d_in[24];
  const void* projgb = d_in[25];
  const void* abias  = d_in[26];

  char* ws = (char*)d_ws;
  size_t off = 0;
  auto alloc = [&](size_t bytes)->void*{
    void* p = ws + off;
    off += (bytes + 255) & ~(size_t)255;
    return p;
  };
  const size_t SM_SMALL = (size_t)4*512*784*2;    // 3.21 MB
  const size_t SM_BIG   = (size_t)4*512*3136*2;   // 12.85 MB
  u16* arenaB  = (u16*)alloc(SM_BIG);             // kpre -> vpre
  u16* arenaC  = (u16*)alloc(SM_SMALL);           // qpre -> hbufT
  u16* colArena= (u16*)alloc((size_t)4*784*4608*2); // 28.9 MB: proj col -> tbufT -> loc col -> obuf
  u16* arenaX  = (u16*)alloc(SM_BIG);             // xT -> vmap
  u16* xproj   = (u16*)alloc(SM_SMALL);
  u16* qnt     = (u16*)alloc(SM_SMALL);
  u16* knt     = (u16*)alloc(SM_BIG);
  u16* vloc    = (u16*)alloc(SM_SMALL);
  float* mbT   = (float*)alloc((size_t)3136*8*4);
  float* lbuf  = (float*)alloc((size_t)4*8*784*4);
  int*   dflag = (int*)alloc(256);
  float* st1   = (float*)alloc(4*32*2*4);
  float* st2   = (float*)alloc(4*32*2*4);
  float* st3   = (float*)alloc(4*32*2*4);
  float* preF32= (float*)alloc((size_t)4*512*784*4);  // 6.42 MB splitK scratch
  u16* qmixbuf = (u16*)alloc((size_t)32*784*512*2);   // 25.7 MB th1-premixed Q

  if(off > ws_size){
    float code = 100000.f + (float)(ws_size >> 20) * 100.f;
    sentinel_k<<<dim3(1),64,0,stream>>>(out16, code);
    return;
  }

  u16* qpre    = arenaC;
  u16* hbufT   = arenaC;             // after qpre dead
  u16* kpre    = arenaB;
  u16* vpre    = arenaB;
  u16* xT      = arenaX;
  u16* vmap    = arenaX;             // after xT dead
  u16* tbufT   = colArena;           // after proj col dead
  float* obuf  = (float*)colArena;   // after loc col dead

  detect_k<<<dim3(1),256,0,stream>>>(x, dflag);

  // xT = transpose(x) bf16
  transp_k<<<dim3(98,8,4),256,0,stream>>>(x, xT, dflag);

  // x_proj = GN(conv3x3s2(x, proj_w) + proj_b) — batched, splitK=3, fused GN
  im2col_bt_k<<<dim3(7056,4),256,0,stream>>>(x, (long)256*3136, colArena, 256, 1, dflag);
  zero_k<<<dim3(1024),256,0,stream>>>(preF32, 4L*512*784);
  gemm_mfma_k<<<dim3(13,24,4),256,0,stream>>>(projw, colArena, preF32, projb,
      512,784,2304, 2304, 0,(long)784*2304,(long)512*784,0, 0,0,64, 3, 0, 1, dflag);
  gn_f784_k<<<dim3(32,4),256,0,stream>>>(preF32, projgw, projgb, nullptr, xproj, dflag, 0);

  // q = l2norm(GN(conv1x1(depthwise+pool) + b)) -> [q][c]
  qlocal_bt_k<<<dim3(3136),256,0,stream>>>(x, qlw, qlb, tbufT, dflag);
  gemm_mfma_k<<<dim3(13,8,4),256,0,stream>>>(qpw, tbufT, qpre, qpb,
      512,784,256, 256, 0,(long)784*256,(long)512*784,0, 0,0,64, 1, 0, 0, dflag);
  gn_stats_k<<<dim3(32,4),256,0,stream>>>(qpre, st1, 784, 0);
  gn_l2t_k<<<dim3(49,4),256,0,stream>>>(qpre, st1, qgw, qgb, qnt, 784, dflag);

  // k = l2norm(GN(conv1x1(x))) -> [n][c]
  gemm_mfma_k<<<dim3(49,8,4),256,0,stream>>>(kw, xT, kpre, nullptr,
      512,3136,256, 256, 0,(long)3136*256,(long)512*3136,0, 0,0,64, 1, 0, 0, dflag);
  gn_stats_k<<<dim3(32,4),256,0,stream>>>(kpre, st2, 3136, 0);
  gn_l2t_k<<<dim3(196,4),256,0,stream>>>(kpre, st2, kgw, kgb, knt, 3136, dflag);

  // v_map = GN(conv1x1(x))
  gemm_mfma_k<<<dim3(49,8,4),256,0,stream>>>(vw, xT, vpre, nullptr,
      512,3136,256, 256, 0,(long)3136*256,(long)512*3136,0, 0,0,64, 1, 0, 0, dflag);
  gn_stats_k<<<dim3(32,4),256,0,stream>>>(vpre, st3, 3136, 0);
  gn_aff_k<<<dim3(3136),256,0,stream>>>(vpre, st3, vgw, vgb, nullptr, vmap, 3136, dflag, 0, 0);

  // v_local = GN(groupconv3x3s2(v_map) + loc_b) — batched, splitK=2, fused GN
  im2col_bt_k<<<dim3(14112,4),256,0,stream>>>(vmap, (long)512*3136, colArena, 512, 0, dflag);
  zero_k<<<dim3(1024),256,0,stream>>>(preF32, 4L*512*784);
  gemm_mfma_k<<<dim3(13,2,32),256,0,stream>>>(locw, colArena, preF32, locb,
      64,784,576, 4608, (long)64*576,576,(long)64*784,64,
      (long)784*4608,(long)512*784,8, 2, 0, 1, dflag);
  gn_f784_k<<<dim3(32,4),256,0,stream>>>(preF32, locgw, locgb, nullptr, vloc, dflag, 0);

  // ---- attention: th1 premix, fused P-free QK/PV, then th2/l mix ----
  mbt_k<<<dim3(98),256,0,stream>>>(th1w, abias, mbT, dflag);
  zero_k<<<dim3(32),256,0,stream>>>(lbuf, 4L*8*784);
  zero_k<<<dim3(1024),256,0,stream>>>(obuf, 4L*512*784);
  qmix_k<<<dim3(6272),256,0,stream>>>(qnt, th1w, qmixbuf, dflag);
  attn2_k<<<dim3(104,4,4),256,0,stream>>>(qmixbuf, knt, vmap, mbT, lbuf, obuf);
  mix_k<<<dim3(784),256,0,stream>>>(obuf, lbuf, th2w, dflag);

  // out = GN(conv1x1(hardswish(attn_out + v_local))) + x_proj — splitK=2, fused GN
  hs_addT_k<<<dim3(25,16,4),256,0,stream>>>(obuf, vloc, hbufT);
  zero_k<<<dim3(1024),256,0,stream>>>(preF32, 4L*512*784);
  gemm_mfma_k<<<dim3(13,16,4),256,0,stream>>>(outw, hbufT, preF32, nullptr,
      512,784,512, 512, 0,(long)784*512,(long)512*784,0, 0,0,64, 2, 0, 1, dflag);
  gn_f784_k<<<dim3(32,4),256,0,stream>>>(preF32, outgw, outgb, xproj, d_out, dflag, 1);

  sanitize_k<<<dim3(1024),256,0,stream>>>(d_out, (long)out_size, dflag);
}